// Round 4
// baseline (767.473 us; speedup 1.0000x reference)
//
#include <hip/hip_runtime.h>

#define BATCH 65536
#define NF 16

typedef __bf16 bf16;
typedef bf16 bf16x8 __attribute__((ext_vector_type(8)));
typedef float f32x4 __attribute__((ext_vector_type(4)));

__device__ __forceinline__ float tanh_fast(float v) {
  // tanh(v) = 1 - 2/(exp(2v)+1); exp(2v) = exp2(v * 2/ln2); rcp(inf)=0 -> exact at +/-large
  float e = exp2f(v * 2.8853900817779268f);
  return 1.0f - 2.0f * __builtin_amdgcn_rcpf(e + 1.0f);
}

// D[batch][feat] = mfma(A=u_frag, B=W_frag), 256 thr / 32 batch rows / block.
// Wave w owns feature tiles {2w, 2w+1}; A-fragments shared across both tiles
// (halves ds_read traffic vs 1-tile/wave). Double-buffered u, 1 barrier/geval.
//
// LDS A-layout with ROW-PERMUTATION swizzle (conflict-free writes):
//   element (row, c) at idx8 = (c>>3)*33 + perm(row), elem = idx8*8 + (c&7)
//   perm(row): bits (rt,quad,r1,r0) -> rt*16 + r0 + quad*2 + r1*8   (bijective)
// Write side (thread owns rows quad*4+r, fixed feat): banks = 8*quad + 4*c3
//   + 2*c2 + c1 -> all 32 banks, 2 lanes/bank = conflict-free.
// Read side: col -> scat(col) per-thread constant; b128 reads stay uniform.
__global__ __launch_bounds__(256) void node_kernel(
    const float* __restrict__ x,
    const float* __restrict__ W0, const float* __restrict__ b0,
    const float* __restrict__ W1, const float* __restrict__ b1,
    const float* __restrict__ Wode, const float* __restrict__ bode,
    float* __restrict__ out)
{
  __shared__ __align__(16) bf16 Au[2][4224];   // 16 cblocks * 33 rows * 8

  const int tid  = threadIdx.x;
  const int lane = tid & 63;
  const int w    = tid >> 6;   // wave 0..3
  const int col  = lane & 15;
  const int quad = lane >> 4;
  const int rowBase = blockIdx.x * 32;

  const float dt  = 1.0f / 15.0f;
  const float dt3 = dt / 3.0f;
  const float e8  = dt * 0.125f;
  const float q8  = dt * dt * 0.125f;

  // read-side permuted row within a 16-row tile (per-thread constant)
  const int scat = (col & 1) + (((col >> 2) & 3) << 1) + (((col >> 1) & 1) << 3);
  // write-side r offsets in elements: perm contribution of r = r0*8 + r1*64
  const int roff[4] = {0, 8, 64, 72};

  int  n[2], abase[2], obase[2];
  bool nok[2];
#pragma unroll
  for (int n2 = 0; n2 < 2; ++n2) {
    n[n2] = (w * 2 + n2) * 16 + col;
    nok[n2] = (n[n2] < 100);
    abase[n2] = ((n[n2] >> 3) * 33 + quad * 2) * 8 + (n[n2] & 7);
    obase[n2] = (rowBase + quad * 4) * (NF * 100) + n[n2];
  }

  // ---- W_ode B-fragments + biases (persistent registers) ----
  bf16x8 bfo[2][4];
  f32x4  bvo[2];
#pragma unroll
  for (int n2 = 0; n2 < 2; ++n2) {
    const float bs = nok[n2] ? bode[n[n2]] : 0.0f;
    bvo[n2] = f32x4{bs, bs, bs, bs};
#pragma unroll
    for (int kc = 0; kc < 4; ++kc)
#pragma unroll
      for (int j = 0; j < 8; ++j) {
        const int k = kc * 32 + quad * 8 + j;
        bfo[n2][kc][j] = (nok[n2] && k < 100) ? (bf16)Wode[n[n2] * 100 + k] : (bf16)0.0f;
      }
  }

  // ---- stage x into Au[0] (coalesced fp32 reads -> swizzled bf16 A-layout) ----
#pragma unroll 1
  for (int i = tid; i < 4096; i += 256) {
    const int r32 = i >> 7;
    const int c   = i & 127;
    const float v = (c < 100) ? x[(rowBase + r32) * 100 + c] : 0.0f;
    const int p = (r32 & 16) + (r32 & 1) + (((r32 >> 2) & 3) << 1) + (((r32 >> 1) & 1) << 3);
    Au[0][((c >> 3) * 33 + p) * 8 + (c & 7)] = (bf16)v;
  }

  f32x4 y0a[2][2], y1a[2][2], k1[2][2], k2[2][2];   // [rt][n2]

  // ---- init: y0 = x@W0^T + b0 ; y1 = x@W1^T + b1 ; seed Au[1]=y0 ; out t=0 ----
  {
    bf16x8 bf0[2][4], bf1[2][4];
    float bias0[2], bias1[2];
#pragma unroll
    for (int n2 = 0; n2 < 2; ++n2) {
      bias0[n2] = nok[n2] ? b0[n[n2]] : 0.0f;
      bias1[n2] = nok[n2] ? b1[n[n2]] : 0.0f;
#pragma unroll
      for (int kc = 0; kc < 4; ++kc)
#pragma unroll
        for (int j = 0; j < 8; ++j) {
          const int k = kc * 32 + quad * 8 + j;
          const bool ok = (nok[n2] && k < 100);
          bf0[n2][kc][j] = ok ? (bf16)W0[n[n2] * 100 + k] : (bf16)0.0f;
          bf1[n2][kc][j] = ok ? (bf16)W1[n[n2] * 100 + k] : (bf16)0.0f;
        }
    }

    __syncthreads();   // x staging visible

#pragma unroll
    for (int rt = 0; rt < 2; ++rt) {
      bf16x8 af[4];
#pragma unroll
      for (int kc = 0; kc < 4; ++kc)
        af[kc] = *(const bf16x8*)&Au[0][((kc * 4 + quad) * 33 + rt * 16 + scat) * 8];
#pragma unroll
      for (int n2 = 0; n2 < 2; ++n2) {
        f32x4 a0 = { bias0[n2], bias0[n2], bias0[n2], bias0[n2] };
        f32x4 a1 = { bias1[n2], bias1[n2], bias1[n2], bias1[n2] };
#pragma unroll
        for (int kc = 0; kc < 4; ++kc) {
          a0 = __builtin_amdgcn_mfma_f32_16x16x32_bf16(af[kc], bf0[n2][kc], a0, 0, 0, 0);
          a1 = __builtin_amdgcn_mfma_f32_16x16x32_bf16(af[kc], bf1[n2][kc], a1, 0, 0, 0);
        }
        y0a[rt][n2] = a0;
        y1a[rt][n2] = a1;
#pragma unroll
        for (int r = 0; r < 4; ++r) {
          Au[1][abase[n2] + rt * 128 + roff[r]] = (bf16)a0[r];   // seed u = y0
          if (nok[n2]) out[obase[n2] + rt * 25600 + r * 1600] = a1[r];
        }
      }
    }
  }
  __syncthreads();   // seed visible

  // One geval: af shared across both feature tiles; MFMA, tanh, FOLD (sets uw,
  // may store out), swizzled write to Au[WR]. Single barrier per geval.
#define GEVAL(RD, WR, ...) do {                                                 \
    _Pragma("unroll")                                                           \
    for (int rt = 0; rt < 2; ++rt) {                                            \
      bf16x8 af[4];                                                             \
      _Pragma("unroll")                                                         \
      for (int kc = 0; kc < 4; ++kc)                                            \
        af[kc] = *(const bf16x8*)&Au[RD][((kc * 4 + quad) * 33 + rt * 16 + scat) * 8]; \
      _Pragma("unroll")                                                         \
      for (int n2 = 0; n2 < 2; ++n2) {                                          \
        f32x4 acc = bvo[n2];                                                    \
        _Pragma("unroll")                                                       \
        for (int kc = 0; kc < 4; ++kc)                                          \
          acc = __builtin_amdgcn_mfma_f32_16x16x32_bf16(af[kc], bfo[n2][kc],    \
                                                        acc, 0, 0, 0);          \
        f32x4 z;                                                                \
        _Pragma("unroll")                                                       \
        for (int r = 0; r < 4; ++r) z[r] = tanh_fast(acc[r]);                   \
        f32x4 uw;                                                               \
        __VA_ARGS__;                                                            \
        _Pragma("unroll")                                                       \
        for (int r = 0; r < 4; ++r)                                             \
          Au[WR][abase[n2] + rt * 128 + roff[r]] = (bf16)uw[r];                 \
      }                                                                         \
    }                                                                           \
    __syncthreads();                                                            \
  } while (0)

#pragma unroll 1
  for (int t = 1; t < NF; ++t) {
    const int ot = t * 100;

    // g1: k1 = g(y0); u2 = y0 + dt/3*k1
    GEVAL(1, 0, {
      k1[rt][n2] = z;
      uw = y0a[rt][n2] + dt3 * z;
    });

    // g2: k2 = g(u2); u3 = y0 + dt*k2 - dt/3*k1
    GEVAL(0, 1, {
      k2[rt][n2] = z;
      uw = y0a[rt][n2] + dt * z - dt3 * k1[rt][n2];
    });

    // g3: k3 = g(u3); u4 = y0 + dt*(k1-k2+k3); fold y1, partial-fold y0; out[t]
    GEVAL(1, 0, {
      const f32x4 a   = k1[rt][n2];
      const f32x4 b2  = k2[rt][n2];
      const f32x4 y0v = y0a[rt][n2];
      uw = y0v + dt * (a - b2 + z);
      const f32x4 ny1 = y1a[rt][n2] + dt * y0v + q8 * (a + 2.0f * b2 + z);
      y1a[rt][n2] = ny1;
      y0a[rt][n2] = y0v + e8 * (a + 3.0f * (b2 + z));
      _Pragma("unroll")
      for (int r = 0; r < 4; ++r)
        if (nok[n2]) out[obase[n2] + rt * 25600 + r * 1600 + ot] = ny1[r];
    });

    // g4: k4 = g(u4); y0 += dt/8*k4; write y0 as next step's u
    GEVAL(0, 1, {
      const f32x4 y0v = y0a[rt][n2] + e8 * z;
      y0a[rt][n2] = y0v;
      uw = y0v;
    });
  }
#undef GEVAL
}

extern "C" void kernel_launch(void* const* d_in, const int* in_sizes, int n_in,
                              void* d_out, int out_size, void* d_ws, size_t ws_size,
                              hipStream_t stream) {
  (void)in_sizes; (void)n_in; (void)out_size; (void)d_ws; (void)ws_size;
  const float* x    = (const float*)d_in[0];
  const float* W0   = (const float*)d_in[1];
  const float* b0   = (const float*)d_in[2];
  const float* W1   = (const float*)d_in[3];
  const float* b1   = (const float*)d_in[4];
  const float* Wode = (const float*)d_in[5];
  const float* bode = (const float*)d_in[6];
  float* out = (float*)d_out;

  dim3 grid(BATCH / 32), block(256);
  hipLaunchKernelGGL(node_kernel, grid, block, 0, stream,
                     x, W0, b0, W1, b1, Wode, bode, out);
}